// Round 9
// baseline (188.572 us; speedup 1.0000x reference)
//
#include <hip/hip_runtime.h>

typedef _Float16 f16;
typedef f16 f16x8 __attribute__((ext_vector_type(8)));
typedef f16 f16x4 __attribute__((ext_vector_type(4)));
typedef float f32x4 __attribute__((ext_vector_type(4)));

// ---------------------------------------------------------------------------
// Prep:
//   s_bf[n][u]      = f16(node_vec[n][u])            (8192 x 128)
//   W1G[w*32+v][u]  = f16(W1s[u][v][w])              (4096 x 128)
//   W2G[w2*32+v][u] = f16(W2[u][v][w2])              (1024 x 128)
// ---------------------------------------------------------------------------
__global__ __launch_bounds__(256) void prep_kernel(
    const float* __restrict__ node_vec, const float* __restrict__ W1s,
    const float* __restrict__ W2, f16* __restrict__ s_bf,
    f16* __restrict__ W1G, f16* __restrict__ W2G)
{
    const int b = blockIdx.x, t = threadIdx.x;
    if (b < 512) {
        int j = b * 256 + t;
        int n = j >> 4, c8 = (j & 15) * 8;
        float4 a = *(const float4*)(node_vec + (size_t)n * 480 + c8);
        float4 c = *(const float4*)(node_vec + (size_t)n * 480 + c8 + 4);
        f16x8 o = { (f16)a.x, (f16)a.y, (f16)a.z, (f16)a.w,
                    (f16)c.x, (f16)c.y, (f16)c.z, (f16)c.w };
        *(f16x8*)(s_bf + (size_t)n * 128 + c8) = o;
    } else if (b < 1024) {
        int bb = b - 512;
        int cb = bb >> 2, u0 = (bb & 3) * 32;
        int v = t >> 3, u = u0 + (t & 7) * 4;
        f16x4 o = { (f16)W1s[(size_t)(u + 0) * 4096 + v * 128 + cb],
                    (f16)W1s[(size_t)(u + 1) * 4096 + v * 128 + cb],
                    (f16)W1s[(size_t)(u + 2) * 4096 + v * 128 + cb],
                    (f16)W1s[(size_t)(u + 3) * 4096 + v * 128 + cb] };
        *(f16x4*)(W1G + (size_t)(32 * cb + v) * 128 + u) = o;
    } else {
        int bb = b - 1024;
        int cb = bb >> 2, u0 = (bb & 3) * 32;
        int v = t >> 3, u = u0 + (t & 7) * 4;
        f16x4 o = { (f16)W2[(size_t)(u + 0) * 1024 + v * 32 + cb],
                    (f16)W2[(size_t)(u + 1) * 1024 + v * 32 + cb],
                    (f16)W2[(size_t)(u + 2) * 1024 + v * 32 + cb],
                    (f16)W2[(size_t)(u + 3) * 1024 + v * 32 + cb] };
        *(f16x4*)(W2G + (size_t)(32 * cb + v) * 128 + u) = o;
    }
}

// ---------------------------------------------------------------------------
// B-stationary G-form GEMM + v-contraction.
//   Block: 128-col strip of B held in LDS (staged once) x NSUB sequential
//   128-row A-subtiles (double-buffered reg->LDS pipeline, 1 barrier/subtile).
//   Wave = 64x64 quadrant: 4 m-tiles x 4 c-tiles, 8 ds_read_b128 / 16 MFMA.
//   Epilogue per subtile: out[n,w] = f( sum_v attr[n,v]*G[n,32w+v]/64 + b[w] )
//   via 16-lane shuffle butterfly.  SILU=1 -> f16 [n][128]; else f32 [n][32].
// ---------------------------------------------------------------------------
template <int NSUB, int SILU>
__global__ __launch_bounds__(256, 1) void gemm_bs(
    const f16* __restrict__ A, const f16* __restrict__ B,
    const float* __restrict__ attr, const float* __restrict__ bias,
    void* __restrict__ out)
{
    __shared__ __align__(16) f16 B_lds[128 * 136];       // 34816 B
    __shared__ __align__(16) f16 A_lds[2][128 * 136];    // 69632 B

    const int t  = threadIdx.x;
    const int N0 = blockIdx.x * (NSUB * 128);
    const int C0 = blockIdx.y * 128;
    const int wv = t >> 6, l = t & 63, lr = l & 15, q = l >> 4;
    const int R0 = 64 * (wv & 1);          // wave's row quadrant (subtile-local)
    const int CL = 64 * (wv >> 1);         // wave's col quadrant (tile-local)

    // ---- stage B once (32 KB), coalesced 16 B/lane, padded rows ----
    #pragma unroll
    for (int i = 0; i < 8; ++i) {
        int idx = t + 256 * i;
        int r = idx >> 4, u0 = (idx & 15) * 8;
        uint4 d = *(const uint4*)(B + (size_t)(C0 + r) * 128 + u0);
        *(uint4*)(B_lds + r * 136 + u0) = d;
    }

    // ---- prologue: A chunk 0 -> regs ----
    uint4 Ar[8];
    #pragma unroll
    for (int j = 0; j < 8; ++j) {
        int idx = t + 256 * j;
        int r = idx >> 4, u0 = (idx & 15) * 8;
        Ar[j] = *(const uint4*)(A + (size_t)(N0 + r) * 128 + u0);
    }

    #pragma unroll
    for (int i = 0; i < NSUB; ++i) {
        const int buf = i & 1;

        // spill regs (chunk i) -> A_lds[buf]
        #pragma unroll
        for (int j = 0; j < 8; ++j) {
            int idx = t + 256 * j;
            int r = idx >> 4, u0 = (idx & 15) * 8;
            *(uint4*)(A_lds[buf] + r * 136 + u0) = Ar[j];
        }
        // issue loads for chunk i+1
        if (i + 1 < NSUB) {
            #pragma unroll
            for (int j = 0; j < 8; ++j) {
                int idx = t + 256 * j;
                int r = idx >> 4, u0 = (idx & 15) * 8;
                Ar[j] = *(const uint4*)(A + (size_t)(N0 + (i + 1) * 128 + r) * 128 + u0);
            }
        }
        __syncthreads();

        // ---- compute: 4 mt x 4 ct, K = 128 over 4 ks steps ----
        f32x4 acc[4][4];
        #pragma unroll
        for (int mt = 0; mt < 4; ++mt)
            #pragma unroll
            for (int ct = 0; ct < 4; ++ct) acc[mt][ct] = f32x4{0, 0, 0, 0};

        #pragma unroll
        for (int ks = 0; ks < 4; ++ks) {
            f16x8 af[4], bf[4];
            #pragma unroll
            for (int mt = 0; mt < 4; ++mt)
                af[mt] = *(const f16x8*)(A_lds[buf] + (R0 + 16 * mt + lr) * 136 + ks * 32 + q * 8);
            #pragma unroll
            for (int ct = 0; ct < 4; ++ct)
                bf[ct] = *(const f16x8*)(B_lds + (CL + 16 * ct + lr) * 136 + ks * 32 + q * 8);
            #pragma unroll
            for (int mt = 0; mt < 4; ++mt)
                #pragma unroll
                for (int ct = 0; ct < 4; ++ct)
                    acc[mt][ct] = __builtin_amdgcn_mfma_f32_16x16x32_f16(
                        af[mt], bf[ct], acc[mt][ct], 0, 0, 0);
        }

        // ---- epilogue: v-contraction + bias (+silu) ----
        #pragma unroll
        for (int mt = 0; mt < 4; ++mt) {
            float at0[4], at1[4];
            #pragma unroll
            for (int reg = 0; reg < 4; ++reg) {
                int row = N0 + i * 128 + R0 + 16 * mt + q * 4 + reg;
                at0[reg] = attr[(size_t)row * 32 + lr];
                at1[reg] = attr[(size_t)row * 32 + 16 + lr];
            }
            #pragma unroll
            for (int w = 0; w < 2; ++w) {
                float pv[4];
                #pragma unroll
                for (int reg = 0; reg < 4; ++reg)
                    pv[reg] = acc[mt][2 * w][reg] * at0[reg]
                            + acc[mt][2 * w + 1][reg] * at1[reg];
                #pragma unroll
                for (int m = 1; m <= 8; m <<= 1)
                    #pragma unroll
                    for (int reg = 0; reg < 4; ++reg)
                        pv[reg] += __shfl_xor(pv[reg], m);
                if (lr == 0) {
                    int wg = blockIdx.y * 4 + (wv >> 1) * 2 + w;
                    float bv = bias[wg];
                    #pragma unroll
                    for (int reg = 0; reg < 4; ++reg) {
                        int row = N0 + i * 128 + R0 + 16 * mt + q * 4 + reg;
                        float val = pv[reg] * 0.015625f + bv;
                        if (SILU) {
                            ((f16*)out)[(size_t)row * 128 + wg] =
                                (f16)(val / (1.f + __expf(-val)));
                        } else {
                            ((float*)out)[(size_t)row * 32 + wg] = val;
                        }
                    }
                }
            }
        }
        __syncthreads();   // before next iter's ds_write reuses buffers
    }
}

// ---------------------------------------------------------------------------
// Head: out[n] = silu(h @ W3/sqrt(32) + b3) @ W4/sqrt(32) + b4
// ---------------------------------------------------------------------------
__global__ __launch_bounds__(256) void head_kernel(
    const float* __restrict__ h, const float* __restrict__ W3,
    const float* __restrict__ b3, const float* __restrict__ W4,
    const float* __restrict__ b4, float* __restrict__ out)
{
    int tid = blockIdx.x * 256 + threadIdx.x;
    int n = tid >> 5, j = tid & 31;
    const float inv = 0.17677669529663687f;  // 1/sqrt(32)
    const float* hr = h + (size_t)n * 32;
    float acc = 0.f;
    #pragma unroll
    for (int i = 0; i < 32; ++i) acc += hr[i] * W3[i * 32 + j];
    float tv = acc * inv + b3[j];
    float g  = tv / (1.f + __expf(-tv));
    float p  = g * W4[j] * inv;
    #pragma unroll
    for (int m = 16; m >= 1; m >>= 1) p += __shfl_xor(p, m, 32);
    if (j == 0) out[n] = p + b4[0];
}

// ---------------------------------------------------------------------------
extern "C" void kernel_launch(void* const* d_in, const int* in_sizes, int n_in,
                              void* d_out, int out_size, void* d_ws, size_t ws_size,
                              hipStream_t stream)
{
    const float* node_vec = (const float*)d_in[0];
    const float* attr     = (const float*)d_in[1];
    const float* W1s      = (const float*)d_in[2];
    const float* b1s      = (const float*)d_in[3];
    // d_in[4..7] (W1g,b1g,W1v1,W1v2) are dead code w.r.t. pred_energy
    const float* W2       = (const float*)d_in[8];
    const float* b2       = (const float*)d_in[9];
    const float* W3       = (const float*)d_in[10];
    const float* b3       = (const float*)d_in[11];
    const float* W4       = (const float*)d_in[12];
    const float* b4       = (const float*)d_in[13];
    float* out = (float*)d_out;

    char* ws = (char*)d_ws;
    f16*   s_bf  = (f16*)(ws);                     // 8192*128*2 = 2 MiB
    f16*   W1G   = (f16*)(ws + (2048u << 10));     // 4096*128*2 = 1 MiB
    f16*   W2G   = (f16*)(ws + (3072u << 10));     // 1024*128*2 = 256 KiB
    f16*   s_act = (f16*)(ws + (3328u << 10));     // 8192*128*2 = 2 MiB
    float* h     = (float*)(ws + (5376u << 10));   // 8192*32*4  = 1 MiB

    prep_kernel<<<1152, 256, 0, stream>>>(node_vec, W1s, W2, s_bf, W1G, W2G);
    // GEMM1: 8 n-chunks x 32 c-strips; 8 subtiles each
    gemm_bs<8, 1><<<dim3(8, 32), 256, 0, stream>>>(s_bf, W1G, attr, b1s, (void*)s_act);
    // GEMM2: 32 n-chunks x 8 c-strips; 2 subtiles each
    gemm_bs<2, 0><<<dim3(32, 8), 256, 0, stream>>>(s_act, W2G, attr, b2, (void*)h);
    head_kernel<<<1024, 256, 0, stream>>>(h, W3, b3, W4, b4, out);
}

// Round 10
// 125.141 us; speedup vs baseline: 1.5069x; 1.5069x over previous
//
#include <hip/hip_runtime.h>

typedef _Float16 f16;
typedef f16 f16x8 __attribute__((ext_vector_type(8)));
typedef f16 f16x2 __attribute__((ext_vector_type(2)));
typedef float f32x4 __attribute__((ext_vector_type(4)));

union F8  { uint4 u4; f16x8 v; f16x2 h[4]; f16 e[8]; };
union U32H { unsigned int u; f16 e[2]; };

// ---------------------------------------------------------------------------
// Prep:
//   s16[n][u]  = f16(node_vec[n][u])      (8192x128)
//   at16[n][v] = f16(attr[n][v])          (8192x32)
//   W1K[w][u*32+v]  = f16(W1s[u][v][w])   (128x4096)  k-major for P-form B
//   W2K[w2][u*32+v] = f16(W2[u][v][w2])   (32x4096)
// ---------------------------------------------------------------------------
__global__ __launch_bounds__(256) void prep_kernel(
    const float* __restrict__ nv, const float* __restrict__ at,
    const float* __restrict__ W1s, const float* __restrict__ W2,
    f16* __restrict__ s16, f16* __restrict__ at16,
    f16* __restrict__ W1K, f16* __restrict__ W2K)
{
    __shared__ f16 T[32 * 136];
    const int b = blockIdx.x, t = threadIdx.x;
    if (b < 512) {                       // s16 cast
        int j = b * 256 + t;
        int n = j >> 4, c8 = (j & 15) * 8;
        float4 a = *(const float4*)(nv + (size_t)n * 480 + c8);
        float4 c = *(const float4*)(nv + (size_t)n * 480 + c8 + 4);
        F8 o; o.v = f16x8{ (f16)a.x, (f16)a.y, (f16)a.z, (f16)a.w,
                           (f16)c.x, (f16)c.y, (f16)c.z, (f16)c.w };
        *(uint4*)(s16 + (size_t)n * 128 + c8) = o.u4;
    } else if (b < 640) {                // at16 cast
        int j = (b - 512) * 256 + t;
        int n = j >> 2, c8 = (j & 3) * 8;
        float4 a = *(const float4*)(at + (size_t)n * 32 + c8);
        float4 c = *(const float4*)(at + (size_t)n * 32 + c8 + 4);
        F8 o; o.v = f16x8{ (f16)a.x, (f16)a.y, (f16)a.z, (f16)a.w,
                           (f16)c.x, (f16)c.y, (f16)c.z, (f16)c.w };
        *(uint4*)(at16 + (size_t)n * 32 + c8) = o.u4;
    } else if (b < 768) {                // W1K: one u per block
        int u = b - 640;
        int v = t >> 3, w0 = (t & 7) * 16;
        #pragma unroll
        for (int e = 0; e < 4; ++e) {
            float4 f = *(const float4*)(W1s + (size_t)(u * 32 + v) * 128 + w0 + e * 4);
            T[v * 136 + w0 + e * 4 + 0] = (f16)f.x;
            T[v * 136 + w0 + e * 4 + 1] = (f16)f.y;
            T[v * 136 + w0 + e * 4 + 2] = (f16)f.z;
            T[v * 136 + w0 + e * 4 + 3] = (f16)f.w;
        }
        __syncthreads();
        int w = t >> 1, v0 = (t & 1) * 16;
        F8 lo, hi;
        #pragma unroll
        for (int e = 0; e < 8; ++e) { lo.e[e] = T[(v0 + e) * 136 + w];
                                      hi.e[e] = T[(v0 + 8 + e) * 136 + w]; }
        *(uint4*)(W1K + (size_t)w * 4096 + u * 32 + v0)     = lo.u4;
        *(uint4*)(W1K + (size_t)w * 4096 + u * 32 + v0 + 8) = hi.u4;
    } else {                             // W2K: one u per block
        int u = b - 768;
        {
            int v = t >> 3, w0 = (t & 7) * 4;
            float4 f = *(const float4*)(W2 + (size_t)(u * 32 + v) * 32 + w0);
            T[v * 40 + w0 + 0] = (f16)f.x;  T[v * 40 + w0 + 1] = (f16)f.y;
            T[v * 40 + w0 + 2] = (f16)f.z;  T[v * 40 + w0 + 3] = (f16)f.w;
        }
        __syncthreads();
        if (t < 64) {
            int w = t >> 1, v0 = (t & 1) * 16;
            F8 lo, hi;
            #pragma unroll
            for (int e = 0; e < 8; ++e) { lo.e[e] = T[(v0 + e) * 40 + w];
                                          hi.e[e] = T[(v0 + 8 + e) * 40 + w]; }
            *(uint4*)(W2K + (size_t)w * 4096 + u * 32 + v0)     = lo.u4;
            *(uint4*)(W2K + (size_t)w * 4096 + u * 32 + v0 + 8) = hi.u4;
        }
    }
}

// ---------------------------------------------------------------------------
// GEMM1 (P-form, k-split): part1[ksl][n][w] = sum_{k in slice} P[n,k]*W1K[w,k]
//   P[n, u*32+v] = s16[n,u]*at16[n,v], generated as register A-frags:
//   A-frag[j] = s_val * atf[j]  (atf K-invariant since v = k&31).
//   Block: 128 rows x 128 w x K-range 512 (8 BK=64 iters, B dbuf in LDS).
//   Wave = 64x64 quadrant. Grid (64, 8) = 512 blocks = 2/CU. 1 barrier/iter.
// ---------------------------------------------------------------------------
__global__ __launch_bounds__(256, 2) void gemm1_kernel(
    const f16* __restrict__ s16, const f16* __restrict__ at16,
    const f16* __restrict__ W1K, float* __restrict__ part1)
{
    __shared__ __align__(16) f16 B_lds[2][128 * 72];   // 36864 B
    __shared__ __align__(16) f16 s_lds[128 * 24];      //  6144 B

    const int t  = threadIdx.x;
    const int n0 = blockIdx.x * 128;
    const int ksl = blockIdx.y;
    const int u0 = ksl * 16;
    const size_t k0 = (size_t)ksl * 512;
    const int wv = t >> 6, l = t & 63, lr = l & 15, q = l >> 4;
    const int R0 = 64 * (wv & 1), CL = 64 * (wv >> 1);

    // B[0] -> regs
    uint4 Br[4];
    #pragma unroll
    for (int j2 = 0; j2 < 4; ++j2) {
        int idx = t + 256 * j2; int r = idx >> 3, c = idx & 7;
        Br[j2] = *(const uint4*)(W1K + (size_t)r * 4096 + k0 + c * 8);
    }
    // s-tile (128 x 16 f16, rows padded to 24)
    { int r = t >> 1, hh = t & 1;
      *(uint4*)(s_lds + r * 24 + hh * 8) =
          *(const uint4*)(s16 + (size_t)(n0 + r) * 128 + u0 + hh * 8); }
    // at-frags (K-invariant)
    F8 atf[4];
    #pragma unroll
    for (int mt = 0; mt < 4; ++mt)
        atf[mt].u4 = *(const uint4*)(at16 + (size_t)(n0 + R0 + 16 * mt + lr) * 32 + q * 8);

    f32x4 acc[4][4];
    #pragma unroll
    for (int mt = 0; mt < 4; ++mt)
        #pragma unroll
        for (int ct = 0; ct < 4; ++ct) acc[mt][ct] = f32x4{0, 0, 0, 0};

    #pragma unroll
    for (int i = 0; i < 8; ++i) {
        const int buf = i & 1;
        #pragma unroll
        for (int j2 = 0; j2 < 4; ++j2) {          // spill B[i] -> LDS
            int idx = t + 256 * j2; int r = idx >> 3, c = idx & 7;
            *(uint4*)(B_lds[buf] + r * 72 + c * 8) = Br[j2];
        }
        if (i + 1 < 8) {                          // load B[i+1]
            #pragma unroll
            for (int j2 = 0; j2 < 4; ++j2) {
                int idx = t + 256 * j2; int r = idx >> 3, c = idx & 7;
                Br[j2] = *(const uint4*)(W1K + (size_t)r * 4096 + k0 + (i + 1) * 64 + c * 8);
            }
        }
        __syncthreads();

        U32H sp[4];                               // s pairs u = 2i, 2i+1
        #pragma unroll
        for (int mt = 0; mt < 4; ++mt)
            sp[mt].u = *(const unsigned int*)(s_lds + (R0 + 16 * mt + lr) * 24 + 2 * i);

        #pragma unroll
        for (int ks = 0; ks < 2; ++ks) {
            F8 bf[4];
            #pragma unroll
            for (int ct = 0; ct < 4; ++ct)
                bf[ct].u4 = *(const uint4*)(B_lds[buf] + (CL + 16 * ct + lr) * 72 + ks * 32 + q * 8);
            #pragma unroll
            for (int mt = 0; mt < 4; ++mt) {
                f16 sv = ks ? sp[mt].e[1] : sp[mt].e[0];
                f16x2 sb = { sv, sv };
                F8 a;
                #pragma unroll
                for (int kk = 0; kk < 4; ++kk) a.h[kk] = sb * atf[mt].h[kk];
                #pragma unroll
                for (int ct = 0; ct < 4; ++ct)
                    acc[mt][ct] = __builtin_amdgcn_mfma_f32_16x16x32_f16(
                        a.v, bf[ct].v, acc[mt][ct], 0, 0, 0);
            }
        }
        // no trailing barrier: next iter writes the other buffer; its own
        // barrier orders write-before-read.
    }

    float* dst = part1 + (size_t)ksl * 1048576;
    #pragma unroll
    for (int mt = 0; mt < 4; ++mt)
        #pragma unroll
        for (int ct = 0; ct < 4; ++ct)
            #pragma unroll
            for (int reg = 0; reg < 4; ++reg)
                dst[(size_t)(n0 + R0 + 16 * mt + q * 4 + reg) * 128 + CL + 16 * ct + lr]
                    = acc[mt][ct][reg];
}

// ---------------------------------------------------------------------------
// GEMM2 (P-form, k-split) with fused slice-reduction+silu A-staging:
//   s2[r][c] = silu( sum_sl part1[sl][n0+r][u0+c] / 64 + b1s[u0+c] )
//   part2[ksl][n][w2] = sum_{k in slice} P2[n,k]*W2K[w2,k],
//   P2[n, u*32+v] = s2[n,u]*at16[n,v].  Block 128 rows x 32 w2 x K 512.
//   B2 (32x512) staged whole. Wave = 32 rows x 32 cols. Grid (64,8).
// ---------------------------------------------------------------------------
__global__ __launch_bounds__(256, 2) void gemm2_kernel(
    const f16* __restrict__ at16, const f16* __restrict__ W2K,
    const float* __restrict__ part1, const float* __restrict__ b1s,
    float* __restrict__ part2)
{
    __shared__ __align__(16) f16 B2[32 * 520];   // 33280 B
    __shared__ __align__(16) f16 s2[128 * 24];   //  6144 B

    const int t  = threadIdx.x;
    const int n0 = blockIdx.x * 128;
    const int ksl = blockIdx.y;
    const int u0 = ksl * 16;
    const size_t k0 = (size_t)ksl * 512;
    const int wv = t >> 6, l = t & 63, lr = l & 15, q = l >> 4;
    const int R0 = 32 * wv;

    #pragma unroll
    for (int j2 = 0; j2 < 8; ++j2) {             // stage B2 (32 KB)
        int idx = t + 256 * j2; int r = idx >> 6, c = idx & 63;
        *(uint4*)(B2 + r * 520 + c * 8) = *(const uint4*)(W2K + (size_t)r * 4096 + k0 + c * 8);
    }
    {                                            // s2: reduce 8 slices + silu
        int r = t >> 1, c8 = (t & 1) * 8;
        const float* p = part1 + (size_t)(n0 + r) * 128 + u0 + c8;
        f32x4 sa = {0, 0, 0, 0}, sb = {0, 0, 0, 0};
        #pragma unroll
        for (int sl = 0; sl < 8; ++sl) {
            sa += *(const f32x4*)(p + (size_t)sl * 1048576);
            sb += *(const f32x4*)(p + (size_t)sl * 1048576 + 4);
        }
        F8 o;
        #pragma unroll
        for (int e = 0; e < 4; ++e) {
            float v = sa[e] * 0.015625f + b1s[u0 + c8 + e];
            o.e[e] = (f16)(v / (1.f + __expf(-v)));
            float w = sb[e] * 0.015625f + b1s[u0 + c8 + 4 + e];
            o.e[4 + e] = (f16)(w / (1.f + __expf(-w)));
        }
        *(uint4*)(s2 + r * 24 + c8) = o.u4;
    }
    F8 atf[2];
    #pragma unroll
    for (int mt = 0; mt < 2; ++mt)
        atf[mt].u4 = *(const uint4*)(at16 + (size_t)(n0 + R0 + 16 * mt + lr) * 32 + q * 8);
    __syncthreads();

    f32x4 acc[2][2];
    #pragma unroll
    for (int mt = 0; mt < 2; ++mt)
        #pragma unroll
        for (int ct = 0; ct < 2; ++ct) acc[mt][ct] = f32x4{0, 0, 0, 0};

    #pragma unroll
    for (int kp = 0; kp < 8; ++kp) {
        U32H sp[2];
        #pragma unroll
        for (int mt = 0; mt < 2; ++mt)
            sp[mt].u = *(const unsigned int*)(s2 + (R0 + 16 * mt + lr) * 24 + 2 * kp);
        #pragma unroll
        for (int kh = 0; kh < 2; ++kh) {
            const int ks = 2 * kp + kh;
            F8 bf[2];
            #pragma unroll
            for (int ct = 0; ct < 2; ++ct)
                bf[ct].u4 = *(const uint4*)(B2 + (16 * ct + lr) * 520 + ks * 32 + q * 8);
            #pragma unroll
            for (int mt = 0; mt < 2; ++mt) {
                f16 sv = kh ? sp[mt].e[1] : sp[mt].e[0];
                f16x2 sb = { sv, sv };
                F8 a;
                #pragma unroll
                for (int kk = 0; kk < 4; ++kk) a.h[kk] = sb * atf[mt].h[kk];
                #pragma unroll
                for (int ct = 0; ct < 2; ++ct)
                    acc[mt][ct] = __builtin_amdgcn_mfma_f32_16x16x32_f16(
                        a.v, bf[ct].v, acc[mt][ct], 0, 0, 0);
            }
        }
    }

    float* dst = part2 + (size_t)ksl * 262144;
    #pragma unroll
    for (int mt = 0; mt < 2; ++mt)
        #pragma unroll
        for (int ct = 0; ct < 2; ++ct)
            #pragma unroll
            for (int reg = 0; reg < 4; ++reg)
                dst[(size_t)(n0 + R0 + 16 * mt + q * 4 + reg) * 32 + 16 * ct + lr]
                    = acc[mt][ct][reg];
}

// ---------------------------------------------------------------------------
// Head: h = sum_sl part2 /64 + b2; out = silu(h W3/sqrt32 + b3) W4/sqrt32 + b4
// ---------------------------------------------------------------------------
__global__ __launch_bounds__(256) void head_kernel(
    const float* __restrict__ part2, const float* __restrict__ b2,
    const float* __restrict__ W3, const float* __restrict__ b3,
    const float* __restrict__ W4, const float* __restrict__ b4,
    float* __restrict__ out)
{
    int tid = blockIdx.x * 256 + threadIdx.x;
    int n = tid >> 5, j = tid & 31;
    float h = 0.f;
    #pragma unroll
    for (int sl = 0; sl < 8; ++sl) h += part2[(size_t)sl * 262144 + (size_t)n * 32 + j];
    h = h * 0.015625f + b2[j];
    float acc = 0.f;
    #pragma unroll
    for (int i = 0; i < 32; ++i) {
        float hi = __shfl(h, i, 32);
        acc += hi * W3[i * 32 + j];
    }
    const float inv = 0.17677669529663687f;  // 1/sqrt(32)
    float tv = acc * inv + b3[j];
    float g  = tv / (1.f + __expf(-tv));
    float p  = g * W4[j] * inv;
    #pragma unroll
    for (int m = 16; m >= 1; m >>= 1) p += __shfl_xor(p, m, 32);
    if (j == 0) out[n] = p + b4[0];
}

// ---------------------------------------------------------------------------
extern "C" void kernel_launch(void* const* d_in, const int* in_sizes, int n_in,
                              void* d_out, int out_size, void* d_ws, size_t ws_size,
                              hipStream_t stream)
{
    const float* node_vec = (const float*)d_in[0];
    const float* attr     = (const float*)d_in[1];
    const float* W1s      = (const float*)d_in[2];
    const float* b1s      = (const float*)d_in[3];
    // d_in[4..7] (W1g,b1g,W1v1,W1v2) are dead code w.r.t. pred_energy
    const float* W2       = (const float*)d_in[8];
    const float* b2       = (const float*)d_in[9];
    const float* W3       = (const float*)d_in[10];
    const float* b3       = (const float*)d_in[11];
    const float* W4       = (const float*)d_in[12];
    const float* b4       = (const float*)d_in[13];
    float* out = (float*)d_out;

    char* ws = (char*)d_ws;
    f16*   s16   = (f16*)(ws);                     // 2 MiB
    f16*   at16  = (f16*)(ws + (2048u << 10));     // 512 KiB
    f16*   W1K   = (f16*)(ws + (2560u << 10));     // 1 MiB
    f16*   W2K   = (f16*)(ws + (3584u << 10));     // 256 KiB
    float* part1 = (float*)(ws + (4096u << 10));   // 8*8192*128*4 = 32 MiB
    float* part2 = (float*)(ws + (36864u << 10));  // 8*8192*32*4  = 8 MiB

    prep_kernel<<<896, 256, 0, stream>>>(node_vec, attr, W1s, W2, s16, at16, W1K, W2K);
    gemm1_kernel<<<dim3(64, 8), 256, 0, stream>>>(s16, at16, W1K, part1);
    gemm2_kernel<<<dim3(64, 8), 256, 0, stream>>>(at16, W2K, part1, b1s, part2);
    head_kernel<<<1024, 256, 0, stream>>>(part2, b2, W3, b3, W4, b4, out);
}